// Round 12
// baseline (279.517 us; speedup 1.0000x reference)
//
#include <hip/hip_runtime.h>
#include <hip/hip_bf16.h>

// QuantLinearAWQ: out[T,N] = x[T,K] @ ((q - z) * s)[K,N] + bias[N]
// T=32, K=4096, N=11008, group=128.
// R11 -> R12: gemm time is invariant to VMEM instr count (R8), wave count
// (R11), pipelining (R9/10) -- but it streams 180 MB of int32 holding 4-bit
// codes. Add a nibble-repack prepass (180 MB -> 22.5 MB, pure streaming
// ~31 us) so the gemm loads ONE uint4 per lane per k-step (4 cols x 8
// nibbles = one MFMA k-fragment per component). Dequant arithmetic is
// bit-identical to R11 -> absmax must stay 0.125. Inner loop stays
// R11-shaped (straight, no hoisting/rotation -- that style is banned).

#define TOKENS   32
#define KDIM     4096
#define NDIM     11008
#define GS       128
#define KSPLIT   8
#define KCHUNK   512               // 4 quant groups per k-block
#define BLOCK    128               // 2 waves
#define BLOCK_N  128               // 86 * 128 == 11008 exactly

typedef __attribute__((ext_vector_type(8))) _Float16 half8;  // MFMA A/B
typedef __attribute__((ext_vector_type(4))) float   floatx4; // MFMA C/D

// ---------- x fp32 -> fp16 (256 KB, L2-resident during gemm) ----------
__global__ __launch_bounds__(256) void awq_cvt_kernel(
    const float* __restrict__ x, unsigned short* __restrict__ xh)
{
    const int i = blockIdx.x * 256 + threadIdx.x;      // grid 128: 32768 float4s
    const float4 v = ((const float4*)x)[i];
    ushort4 o;
    o.x = __builtin_bit_cast(unsigned short, (_Float16)v.x);
    o.y = __builtin_bit_cast(unsigned short, (_Float16)v.y);
    o.z = __builtin_bit_cast(unsigned short, (_Float16)v.z);
    o.w = __builtin_bit_cast(unsigned short, (_Float16)v.w);
    ((ushort4*)xh)[i] = o;
}

// ---------- nibble repack: pw[k/8][n] u32, bit[4j..] = qw[8*(k/8)+j][n] ----
// Pure streaming: 180 MB coalesced read, 22.5 MB coalesced write.
__global__ __launch_bounds__(256) void awq_pack_kernel(
    const int* __restrict__ qw, unsigned* __restrict__ pw)
{
    const int n  = blockIdx.x * 256 + threadIdx.x;     // grid (43, 512)
    const int ko = blockIdx.y;
    const int* qp = qw + (size_t)ko * 8 * NDIM + n;
    unsigned w = 0;
    #pragma unroll
    for (int j = 0; j < 8; ++j)
        w |= ((unsigned)qp[(size_t)j * NDIM] & 0xFu) << (4 * j);
    pw[(size_t)ko * NDIM + n] = w;
}

// ---------- MFMA dequant-GEMM (packed weights) ----------
// A-frag: A[m=lane&15][k=quad*8+j]; C/D: col=lane&15, row=quad*4+reg.
// B symmetric to A. Column remap (R8-verified): MFMA-col c, tile nt ->
// memory column n = nb + 4*c + nt. One uint4 per (k-step, lane): component
// t = column nc+t, nibble j = k-row quad*8+j of the 32-row step.
__global__ __launch_bounds__(BLOCK) void awq_gemm_mfma(
    const unsigned short* __restrict__ xh,   // [T][K] fp16 bits
    const unsigned* __restrict__ pw,         // [K/8][N] packed nibbles
    const int*   __restrict__ qz,            // [K/GS][N]
    const float* __restrict__ sc,            // [K/GS][N]
    float*       __restrict__ dst)           // part [KSPLIT][T][N]
{
    const int tid  = threadIdx.x;
    const int lane = tid & 63;
    const int wv   = tid >> 6;               // 0..1
    const int col  = lane & 15;
    const int quad = lane >> 4;              // 0..3
    const int nb   = blockIdx.x * BLOCK_N + wv * 64;
    const int nc   = nb + 4 * col;           // 4 consecutive columns per lane

    floatx4 acc[4][2];
    #pragma unroll
    for (int nt = 0; nt < 4; ++nt) {
        acc[nt][0] = (floatx4){0.f, 0.f, 0.f, 0.f};
        acc[nt][1] = (floatx4){0.f, 0.f, 0.f, 0.f};
    }

    for (int gi = 0; gi < KCHUNK / GS; ++gi) {
        const int g   = blockIdx.y * (KCHUNK / GS) + gi;
        const int kc0 = g * GS;

        // scalar s/z loads at the remapped columns; (q-8)-(z-8) == q-z
        float s[4], nzs[4];
        #pragma unroll
        for (int nt = 0; nt < 4; ++nt) {
            const int n  = nc + nt;
            const float sv = sc[(size_t)g * NDIM + n];
            const int   zv = qz[(size_t)g * NDIM + n];
            s[nt] = sv; nzs[nt] = -(float)zv * sv;
        }

        // octet row for MFMA step ks, this lane: kc0/8 + ks*4 + quad
        const unsigned* wbase = pw + (size_t)((kc0 >> 3) + quad) * NDIM + nc;
        const unsigned short* xr0 = xh + (size_t)col * KDIM + kc0 + quad * 8;
        const unsigned short* xr1 = xr0 + 16 * KDIM;   // tokens 16-31

        #pragma unroll 2
        for (int ks = 0; ks < GS / 32; ++ks) {   // 4 k-steps of 32
            const uint4 pq = *(const uint4*)(wbase + (size_t)(ks * 4) * NDIM);

            const half8 a0 = *(const half8*)(xr0 + ks * 32);   // tokens 0-15
            const half8 a1 = *(const half8*)(xr1 + ks * 32);   // tokens 16-31

            half8 b0, b1, b2, b3;
            #pragma unroll
            for (int j = 0; j < 8; ++j) {
                b0[j] = (_Float16)fmaf((float)((pq.x >> (4 * j)) & 15u), s[0], nzs[0]);
                b1[j] = (_Float16)fmaf((float)((pq.y >> (4 * j)) & 15u), s[1], nzs[1]);
                b2[j] = (_Float16)fmaf((float)((pq.z >> (4 * j)) & 15u), s[2], nzs[2]);
                b3[j] = (_Float16)fmaf((float)((pq.w >> (4 * j)) & 15u), s[3], nzs[3]);
            }
            acc[0][0] = __builtin_amdgcn_mfma_f32_16x16x32_f16(a0, b0, acc[0][0], 0, 0, 0);
            acc[0][1] = __builtin_amdgcn_mfma_f32_16x16x32_f16(a1, b0, acc[0][1], 0, 0, 0);
            acc[1][0] = __builtin_amdgcn_mfma_f32_16x16x32_f16(a0, b1, acc[1][0], 0, 0, 0);
            acc[1][1] = __builtin_amdgcn_mfma_f32_16x16x32_f16(a1, b1, acc[1][1], 0, 0, 0);
            acc[2][0] = __builtin_amdgcn_mfma_f32_16x16x32_f16(a0, b2, acc[2][0], 0, 0, 0);
            acc[2][1] = __builtin_amdgcn_mfma_f32_16x16x32_f16(a1, b2, acc[2][1], 0, 0, 0);
            acc[3][0] = __builtin_amdgcn_mfma_f32_16x16x32_f16(a0, b3, acc[3][0], 0, 0, 0);
            acc[3][1] = __builtin_amdgcn_mfma_f32_16x16x32_f16(a1, b3, acc[3][1], 0, 0, 0);
        }
    }

    // token = h*16 + quad*4 + r; columns nc..nc+3 = tiles 0..3 -> float4
    float* pbase = dst + (size_t)blockIdx.y * TOKENS * NDIM;
    #pragma unroll
    for (int h = 0; h < 2; ++h)
        #pragma unroll
        for (int r = 0; r < 4; ++r) {
            const float4 v = make_float4(acc[0][h][r], acc[1][h][r],
                                         acc[2][h][r], acc[3][h][r]);
            *(float4*)(pbase + (size_t)(h * 16 + quad * 4 + r) * NDIM + nc) = v;
        }
}

// ---------- reduce KSPLIT partials + bias ----------
__global__ __launch_bounds__(256) void awq_reduce_kernel(
    const float* __restrict__ part,   // [KSPLIT][T][N]
    const float* __restrict__ bias,
    float*       __restrict__ out)    // [T][N]
{
    const int o = blockIdx.x * 256 + threadIdx.x;   // float4 idx, 88064 total
    const int t = o / (NDIM / 4);
    const int c = o - t * (NDIM / 4);
    const float4* p4 = (const float4*)part;
    float4 sum = ((const float4*)bias)[c];
    #pragma unroll
    for (int s = 0; s < KSPLIT; ++s) {
        const float4 v = p4[(size_t)(s * TOKENS + t) * (NDIM / 4) + c];
        sum.x += v.x; sum.y += v.y; sum.z += v.z; sum.w += v.w;
    }
    ((float4*)out)[o] = sum;
}

extern "C" void kernel_launch(void* const* d_in, const int* in_sizes, int n_in,
                              void* d_out, int out_size, void* d_ws, size_t ws_size,
                              hipStream_t stream) {
    const float* x    = (const float*)d_in[0];
    const int*   qw   = (const int*)  d_in[1];
    const int*   qz   = (const int*)  d_in[2];
    const float* sc   = (const float*)d_in[3];
    const float* bias = (const float*)d_in[4];
    float* out = (float*)d_out;

    const size_t xh_bytes = 512 * 1024;                                  // 256 KB used
    const size_t pw_bytes = (size_t)(KDIM / 8) * NDIM * sizeof(unsigned); // 22.5 MB
    const size_t part_bytes = (size_t)KSPLIT * TOKENS * NDIM * sizeof(float); // 11.3 MB
    unsigned short* xh = (unsigned short*)d_ws;
    unsigned* pwp = (unsigned*)((char*)d_ws + xh_bytes);
    float* part = (float*)((char*)d_ws + xh_bytes + pw_bytes);
    (void)ws_size; (void)part_bytes;   // harness ws (704 MB) >> 34 MB needed

    awq_cvt_kernel<<<(TOKENS * KDIM / 4) / 256, 256, 0, stream>>>(x, xh);
    awq_pack_kernel<<<dim3(NDIM / 256, KDIM / 8), 256, 0, stream>>>(qw, pwp);
    awq_gemm_mfma<<<dim3(NDIM / BLOCK_N, KSPLIT), BLOCK, 0, stream>>>(
        xh, pwp, qz, sc, part);
    awq_reduce_kernel<<<(TOKENS * NDIM / 4) / 256, 256, 0, stream>>>(
        part, bias, out);
}